// Round 3
// baseline (4595.300 us; speedup 1.0000x reference)
//
#include <hip/hip_runtime.h>
#include <cmath>

// RouterCond fused, round 3: fp16x2-split MFMA GEMMs, 2 blocks/CU occupancy.
// x[32768x1536] @ W1^T -> GELU -> @ W2^T[3072x64] -> softmax -> top2.
#define N_TOK 32768
#define D0    1024
#define DCC   512
#define DIN   1536
#define JD    3072
#define NE    64
#define BM    64           // tokens per block (512 blocks -> 2 blocks/CU)
#define BJ    256          // j-chunk (x re-read only 12x)
#define KC    32           // k-step
#define NJC   (JD/BJ)      // 12
#define NKS   (DIN/KC)     // 48
#define NTH   512
#define ALD   36           // A1 row stride in halves (18 dwords % 32 -> 2-way, free)
#define BLD   36
#define HLD   68           // H row stride in halves (34 dwords % 32 = 2 -> 2-way)
#define NSL   4            // GEMM2 j-slices per jc (64 j each)
#define EPSV  1e-9f

typedef _Float16 half8  __attribute__((ext_vector_type(8)));
typedef _Float16 half4v __attribute__((ext_vector_type(4)));
typedef float    f32x4  __attribute__((ext_vector_type(4)));

// LDS byte offsets (total 65024 B -> 2 blocks/CU on 160 KiB)
#define OFF_A1H 0
#define OFF_A1L (OFF_A1H + BM*ALD*2)      // 4608
#define OFF_B1H (OFF_A1L + BM*ALD*2)      // 9216
#define OFF_B1L (OFF_B1H + BJ*BLD*2)      // 27648
#define OFF_H   (OFF_B1L + BJ*BLD*2)      // 46080
#define OFF_HL  (OFF_H   + BM*HLD*2)      // 54784
#define OFF_EPI (OFF_HL  + BM*HLD*2)      // 63488
#define LDS_TOTAL (OFF_EPI + 6*BM*4)      // 65024
#define OFF_LRED OFF_H                     // [64][68] f32 = 17408, aliases H (dead)

__device__ __forceinline__ f32x4 mfma16(half8 a, half8 b, f32x4 c) {
    return __builtin_amdgcn_mfma_f32_16x16x32_f16(a, b, c, 0, 0, 0);
}

__device__ __forceinline__ void split4(const float4 v, half4v& hh, half4v& hl) {
    float f[4] = {v.x, v.y, v.z, v.w};
    #pragma unroll
    for (int i = 0; i < 4; ++i) {
        _Float16 h = (_Float16)f[i];
        hh[i] = h;
        hl[i] = (_Float16)(f[i] - (float)h);
    }
}

__device__ __forceinline__ void split8(const float4 v0, const float4 v1, half8& hh, half8& hl) {
    float f[8] = {v0.x, v0.y, v0.z, v0.w, v1.x, v1.y, v1.z, v1.w};
    #pragma unroll
    for (int i = 0; i < 8; ++i) {
        _Float16 h = (_Float16)f[i];
        hh[i] = h;
        hl[i] = (_Float16)(f[i] - (float)h);
    }
}

__global__ __launch_bounds__(NTH, 4)
void router_v3(const float* __restrict__ inp, const float* __restrict__ cnd,
               const float* __restrict__ W1, const float* __restrict__ W2,
               float* __restrict__ out_mask, float* __restrict__ out_topi,
               float* __restrict__ out_rp, float* __restrict__ out_probs)
{
    __shared__ __align__(16) char smem[LDS_TOTAL];
    _Float16* const A1h = (_Float16*)(smem + OFF_A1H);
    _Float16* const A1l = (_Float16*)(smem + OFF_A1L);
    _Float16* const B1h = (_Float16*)(smem + OFF_B1H);
    _Float16* const B1l = (_Float16*)(smem + OFF_B1L);
    _Float16* const Hh  = (_Float16*)(smem + OFF_H);
    _Float16* const Hl  = (_Float16*)(smem + OFF_HL);

    const int tid  = threadIdx.x;
    const int lane = tid & 63;
    const int w    = tid >> 6;      // wave 0..7
    const int tg   = w >> 2;        // token half: rows tg*32..+31
    const int jg   = w & 3;         // j quarter (64 cols) / expert group (16 experts)
    const int l15  = lane & 15;
    const int lg   = lane >> 4;     // 0..3
    const int t0   = blockIdx.x * BM;

    // GEMM1 staging: A 64x32 floats (1 float4/thread), B 256x32 (4 float4/thread)
    const int arow = tid >> 3, ak4  = (tid & 7) * 4;
    const int brow = tid >> 1, bk16 = (tid & 1) * 16;

    // MFMA fragment LDS offsets (A: row=lane&15, k=(lane>>4)*8+b; B: col=lane&15)
    int aoff[2], boff[4];
    #pragma unroll
    for (int tf = 0; tf < 2; ++tf) aoff[tf] = (tg*32 + tf*16 + l15) * ALD + lg*8;
    #pragma unroll
    for (int jf = 0; jf < 4; ++jf) boff[jf] = (jg*64 + jf*16 + l15) * BLD + lg*8;

    const f32x4 vzero = {0.f, 0.f, 0.f, 0.f};
    f32x4 lacc[2] = {vzero, vzero};   // logits: rows tg*32+tf*16.., experts jg*16+l15

    const float* const xA = inp + (size_t)(t0 + arow) * D0;
    const float* const xC = cnd + (size_t)(t0 + arow) * DCC;

    for (int jc = 0; jc < NJC; ++jc) {
        const float* const w1r = W1 + (size_t)(jc*BJ + brow) * DIN;

        f32x4 acc1[2][4];
        #pragma unroll
        for (int tf = 0; tf < 2; ++tf)
            #pragma unroll
            for (int jf = 0; jf < 4; ++jf) acc1[tf][jf] = vzero;

        // prologue: stage k-step 0 (always inp side)
        float4 ra  = *(const float4*)(xA + ak4);
        float4 rb0 = *(const float4*)(w1r + bk16);
        float4 rb1 = *(const float4*)(w1r + bk16 + 4);
        float4 rb2 = *(const float4*)(w1r + bk16 + 8);
        float4 rb3 = *(const float4*)(w1r + bk16 + 12);
        {
            half4v h4, l4;
            split4(ra, h4, l4);
            *(half4v*)(A1h + arow*ALD + ak4) = h4;
            *(half4v*)(A1l + arow*ALD + ak4) = l4;
            half8 h8, l8;
            split8(rb0, rb1, h8, l8);
            *(half8*)(B1h + brow*BLD + bk16) = h8;
            *(half8*)(B1l + brow*BLD + bk16) = l8;
            split8(rb2, rb3, h8, l8);
            *(half8*)(B1h + brow*BLD + bk16 + 8) = h8;
            *(half8*)(B1l + brow*BLD + bk16 + 8) = l8;
        }
        __syncthreads();

        for (int ks = 0; ks < NKS; ++ks) {
            const bool more = (ks + 1 < NKS);
            if (more) {   // prefetch next k-step into regs
                const int k = (ks + 1) * KC;
                const float* sA = (k + ak4 < D0) ? (xA + k + ak4) : (xC + k + ak4 - D0);
                ra  = *(const float4*)sA;
                rb0 = *(const float4*)(w1r + k + bk16);
                rb1 = *(const float4*)(w1r + k + bk16 + 4);
                rb2 = *(const float4*)(w1r + k + bk16 + 8);
                rb3 = *(const float4*)(w1r + k + bk16 + 12);
            }
            half8 ah[2], al[2], bh[4], bl[4];
            #pragma unroll
            for (int tf = 0; tf < 2; ++tf) {
                ah[tf] = *(const half8*)(A1h + aoff[tf]);
                al[tf] = *(const half8*)(A1l + aoff[tf]);
            }
            #pragma unroll
            for (int jf = 0; jf < 4; ++jf) {
                bh[jf] = *(const half8*)(B1h + boff[jf]);
                bl[jf] = *(const half8*)(B1l + boff[jf]);
            }
            #pragma unroll
            for (int tf = 0; tf < 2; ++tf)
                #pragma unroll
                for (int jf = 0; jf < 4; ++jf) {
                    acc1[tf][jf] = mfma16(ah[tf], bh[jf], acc1[tf][jf]);
                    acc1[tf][jf] = mfma16(ah[tf], bl[jf], acc1[tf][jf]);
                    acc1[tf][jf] = mfma16(al[tf], bh[jf], acc1[tf][jf]);
                }
            __syncthreads();               // frag reads done -> safe to overwrite
            if (more) {
                half4v h4, l4;
                split4(ra, h4, l4);
                *(half4v*)(A1h + arow*ALD + ak4) = h4;
                *(half4v*)(A1l + arow*ALD + ak4) = l4;
                half8 h8, l8;
                split8(rb0, rb1, h8, l8);
                *(half8*)(B1h + brow*BLD + bk16) = h8;
                *(half8*)(B1l + brow*BLD + bk16) = l8;
                split8(rb2, rb3, h8, l8);
                *(half8*)(B1h + brow*BLD + bk16 + 8) = h8;
                *(half8*)(B1l + brow*BLD + bk16 + 8) = l8;
                __syncthreads();           // writes visible
            }
        }

        // ---- GEMM2 in 4 j-slices of 64; W2 frags straight from global (L2-resident)
        const float* const w2p = W2 + (size_t)(jg*16 + l15) * JD + jc*BJ;
        #pragma unroll
        for (int s = 0; s < NSL; ++s) {
            // issue W2 loads for this slice (hidden under barrier + H write)
            float4 wq0 = *(const float4*)(w2p + s*64 + lg*8);
            float4 wq1 = *(const float4*)(w2p + s*64 + lg*8 + 4);
            float4 wq2 = *(const float4*)(w2p + s*64 + 32 + lg*8);
            float4 wq3 = *(const float4*)(w2p + s*64 + 32 + lg*8 + 4);

            if (jg == s) {   // this wave group owns slice s: GELU + split + write H
                #pragma unroll
                for (int tf = 0; tf < 2; ++tf)
                    #pragma unroll
                    for (int jf = 0; jf < 4; ++jf)
                        #pragma unroll
                        for (int r = 0; r < 4; ++r) {
                            const float v = acc1[tf][jf][r];
                            const float g = 0.5f * v * (1.0f + erff(v * 0.70710678118654752f));
                            const _Float16 gh = (_Float16)g;
                            const _Float16 gl = (_Float16)(g - (float)gh);
                            const int o = (tg*32 + tf*16 + lg*4 + r) * HLD + jf*16 + l15;
                            Hh[o] = gh; Hl[o] = gl;
                        }
            }
            __syncthreads();
            #pragma unroll
            for (int ks2 = 0; ks2 < 2; ++ks2) {
                half8 b2h, b2l;
                split8(ks2 ? wq2 : wq0, ks2 ? wq3 : wq1, b2h, b2l);
                #pragma unroll
                for (int tf = 0; tf < 2; ++tf) {
                    const int o = (tg*32 + tf*16 + l15) * HLD + ks2*32 + lg*8;
                    half8 a2h = *(const half8*)(Hh + o);
                    half8 a2l = *(const half8*)(Hl + o);
                    lacc[tf] = mfma16(a2h, b2h, lacc[tf]);
                    lacc[tf] = mfma16(a2h, b2l, lacc[tf]);
                    lacc[tf] = mfma16(a2l, b2h, lacc[tf]);
                }
            }
            __syncthreads();   // H reads done before next slice overwrites
        }
    }

    // ---- epilogue: gather logits, softmax + top-2, write 4 outputs
    float* const Lred = (float*)(smem + OFF_LRED);
    #pragma unroll
    for (int tf = 0; tf < 2; ++tf)
        #pragma unroll
        for (int r = 0; r < 4; ++r)
            Lred[(tg*32 + tf*16 + lg*4 + r) * HLD + jg*16 + l15] = lacc[tf][r];
    __syncthreads();

    float* const mA   = (float*)(smem + OFF_EPI);
    float* const invA = mA + BM;
    int*   const i1A  = (int*)(invA + BM);
    int*   const i2A  = i1A + BM;
    float* const rp1A = (float*)(i2A + BM);
    float* const rp2A = rp1A + BM;

    if (tid < BM) {
        const float* row = Lred + tid * HLD;
        float m = -3.402823466e38f;
        for (int e = 0; e < NE; ++e) m = fmaxf(m, row[e]);
        float s = 0.f, v1 = -3.402823466e38f, v2 = -3.402823466e38f;
        int i1 = 0, i2 = 0;
        for (int e = 0; e < NE; ++e) {
            const float v = row[e];
            s += expf(v - m);
            if (v > v1)      { v2 = v1; i2 = i1; v1 = v; i1 = e; }
            else if (v > v2) { v2 = v; i2 = e; }
        }
        const float inv = 1.f / s;
        const float p1 = fminf(expf(v1 - m) * inv + EPSV, 1.f - EPSV);
        const float p2 = fminf(expf(v2 - m) * inv + EPSV, 1.f - EPSV);
        mA[tid] = m; invA[tid] = inv; i1A[tid] = i1; i2A[tid] = i2;
        const float den = p1 + p2;
        rp1A[tid] = p1 / den; rp2A[tid] = p2 / den;
    }
    __syncthreads();

    for (int idx = tid; idx < BM * NE; idx += NTH) {
        const int r = idx >> 6, e = idx & 63;
        const size_t o = (size_t)(t0 + r) * NE + e;
        const float p = fminf(expf(Lred[r * HLD + e] - mA[r]) * invA[r] + EPSV, 1.f - EPSV);
        const int b1 = (e == i1A[r]), b2 = (e == i2A[r]);
        out_probs[o] = p;
        out_mask[o]  = (b1 | b2) ? 1.f : 0.f;
        out_rp[o]    = b1 ? rp1A[r] : (b2 ? rp2A[r] : 0.f);
    }
    if (tid < BM * 2) {
        const int r = tid >> 1, q = tid & 1;
        out_topi[(size_t)(t0 + r) * 2 + q] = (float)(q ? i2A[r] : i1A[r]);
    }
}

extern "C" void kernel_launch(void* const* d_in, const int* in_sizes, int n_in,
                              void* d_out, int out_size, void* d_ws, size_t ws_size,
                              hipStream_t stream) {
    const float* inp = (const float*)d_in[0];
    const float* cnd = (const float*)d_in[1];
    const float* W1  = (const float*)d_in[2];
    const float* W2  = (const float*)d_in[3];

    float* out = (float*)d_out;
    const size_t NT = (size_t)N_TOK;
    float* out_mask  = out;
    float* out_topi  = out + NT * NE;
    float* out_rp    = out + NT * NE + NT * 2;
    float* out_probs = out + NT * NE + NT * 2 + NT * NE;

    dim3 grid(N_TOK / BM);   // 512 blocks -> 2 per CU
    dim3 block(NTH);
    hipLaunchKernelGGL(router_v3, grid, block, 0, stream,
                       inp, cnd, W1, W2, out_mask, out_topi, out_rp, out_probs);
}